// Round 13
// baseline (942.556 us; speedup 1.0000x reference)
//
#include <hip/hip_runtime.h>

#define D_ 512
#define ND_ 2048   // 4*D
#define KS_ 24
#define TB_ 32
#define B_ 8192
#define NU_ 33     // 32 K-units of Wu + 1 ext unit [Wx; b]

typedef __attribute__((ext_vector_type(8))) short short8;
typedef __attribute__((ext_vector_type(16))) float f32x16;
typedef unsigned short u16;

// byte offset into swizzled h tile: row in [0,32), kb = byte offset along d (d*2)
#define SWZ(row, kb) (((row) * 1024) + ((kb) ^ (((row) & 15) << 4)))

__device__ __forceinline__ u16 f2bf(float f) {
  union { float f; unsigned int u; } v; v.f = f;
  unsigned int u = v.u;
  return (u16)((u + 0x7FFFu + ((u >> 16) & 1u)) >> 16);
}

__device__ __forceinline__ float sigm(float x) { return 1.0f / (1.0f + __expf(-x)); }
__device__ __forceinline__ float tanh_(float x) {
  float e = __expf(2.0f * x);
  return (e - 1.0f) / (e + 1.0f);
}

// Pack [Wu; Wx; b] into MFMA B-fragment order, bf16. (unchanged from R8)
__global__ __launch_bounds__(256) void pack_wu_kernel(const float* __restrict__ Wu,
                                                      const float* __restrict__ Wx,
                                                      const float* __restrict__ b,
                                                      u16* __restrict__ pk) {
  int idx = blockIdx.x * 256 + threadIdx.x;
  int lane = idx & 63;
  int unit = idx >> 6;        // 0..2111 = nt*33 + un
  if (unit >= 64 * NU_) return;
  int nt = unit / NU_;
  int un = unit - nt * NU_;
  int col = nt * 32 + (lane & 31);
  u16 t[8] = {0, 0, 0, 0, 0, 0, 0, 0};
  if (un < 32) {
    int k0 = un * 16 + (lane >> 5) * 8;
#pragma unroll
    for (int j = 0; j < 8; ++j) t[j] = f2bf(Wu[(size_t)(k0 + j) * ND_ + col]);
  } else if ((lane >> 5) == 0) {
    t[0] = f2bf(Wx[col]);
    t[1] = f2bf(b[col]);
  }
  int4 w;
  w.x = t[0] | (t[1] << 16); w.y = t[2] | (t[3] << 16);
  w.z = t[4] | (t[5] << 16); w.w = t[6] | (t[7] << 16);
  *reinterpret_cast<int4*>(pk + (size_t)unit * 512 + lane * 8) = w;
}

#define LD8(P, u) (*reinterpret_cast<const short8*>((P) + (size_t)(u) * 512))
#define AH(ks) (*reinterpret_cast<const short8*>(&hr[SWZ(l31, (ks) * 32 + abase)]))
#define MFMA_(A, B, C) __builtin_amdgcn_mfma_f32_32x32x16_bf16(A, B, C, 0, 0, 0)

// prologue: issue K-units 0,1,2 of the 4 gate streams (12 loads, 12 KB/wave)
#define KPRO(P0, P1, P2, P3)                                                   \
    fA0 = LD8(P0, 0); fA1 = LD8(P1, 0); fA2 = LD8(P2, 0); fA3 = LD8(P3, 0);    \
    fB0 = LD8(P0, 1); fB1 = LD8(P1, 1); fB2 = LD8(P2, 1); fB3 = LD8(P3, 1);    \
    fC0 = LD8(P0, 2); fC1 = LD8(P1, 2); fC2 = LD8(P2, 2); fC3 = LD8(P3, 2);

// gate math + per-4-row y-reduction (8 live y scalars). CLOAD/CSTORE are
// expressions over (r, row) giving the cell-state access for this pass.
#define GATE_REDUCE(CLOAD, CSTORE, COL, W1V, W2V, PIDX)                        \
    _Pragma("unroll")                                                          \
    for (int rb = 0; rb < 16; rb += 4) {                                       \
      float y1t[4], y2t[4];                                                    \
      _Pragma("unroll")                                                        \
      for (int q = 0; q < 4; ++q) {                                            \
        const int r = rb + q;                                                  \
        const int row = q + 8 * (rb >> 2) + 4 * lhi;                           \
        float ig = sigm(acc0[r]);                                              \
        float fg = sigm(acc1[r]);                                              \
        float gg = tanh_(acc2[r]);                                             \
        float og = sigm(acc3[r]);                                              \
        float cn = fg * (CLOAD) + ig * gg;                                     \
        CSTORE;                                                                \
        float hn = og * tanh_(cn);                                             \
        *reinterpret_cast<u16*>(&hw[SWZ(row, (COL) * 2)]) = f2bf(hn);          \
        y1t[q] = hn * (W1V);                                                   \
        y2t[q] = hn * (W2V);                                                   \
      }                                                                        \
      _Pragma("unroll")                                                        \
      for (int m = 1; m < 32; m <<= 1) {                                       \
        _Pragma("unroll")                                                      \
        for (int q = 0; q < 4; ++q) {                                          \
          y1t[q] += __shfl_xor(y1t[q], m);                                     \
          y2t[q] += __shfl_xor(y2t[q], m);                                     \
        }                                                                      \
      }                                                                        \
      if (l31 == 0) {                                                          \
        _Pragma("unroll")                                                      \
        for (int q = 0; q < 4; ++q) {                                          \
          const int row = q + 8 * (rb >> 2) + 4 * lhi;                         \
          ly1[PIDX][wvu][row] = y1t[q];                                        \
          ly2[PIDX][wvu][row] = y2t[q];                                        \
        }                                                                      \
      }                                                                        \
    }

// one pass over 33 K-units, 3-buffer rotation, consume-then-reissue: each
// buffer is issued ~2 full iterations before its MFMA consumes it (12 loads
// = 12 KB/wave outstanding). NEXTPRO issues the next pass's prologue before
// this pass's gate math so the inter-pass bubble is covered.
#define KBODY(P0, P1, P2, P3, NEXTPRO)                                         \
  {                                                                            \
    acc0 = (f32x16){}; acc1 = (f32x16){}; acc2 = (f32x16){}; acc3 = (f32x16){};\
    _Pragma("unroll 1")                                                        \
    for (int ks = 0; ks < 30; ks += 3) {                                       \
      short8 a0 = AH(ks);                                                      \
      acc0 = MFMA_(a0, fA0, acc0); acc1 = MFMA_(a0, fA1, acc1);                \
      acc2 = MFMA_(a0, fA2, acc2); acc3 = MFMA_(a0, fA3, acc3);                \
      fA0 = LD8(P0, ks + 3); fA1 = LD8(P1, ks + 3);                            \
      fA2 = LD8(P2, ks + 3); fA3 = LD8(P3, ks + 3);                            \
      short8 a1 = AH(ks + 1);                                                  \
      acc0 = MFMA_(a1, fB0, acc0); acc1 = MFMA_(a1, fB1, acc1);                \
      acc2 = MFMA_(a1, fB2, acc2); acc3 = MFMA_(a1, fB3, acc3);                \
      fB0 = LD8(P0, ks + 4); fB1 = LD8(P1, ks + 4);                            \
      fB2 = LD8(P2, ks + 4); fB3 = LD8(P3, ks + 4);                            \
      short8 a2 = AH(ks + 2);                                                  \
      acc0 = MFMA_(a2, fC0, acc0); acc1 = MFMA_(a2, fC1, acc1);                \
      acc2 = MFMA_(a2, fC2, acc2); acc3 = MFMA_(a2, fC3, acc3);                \
      fC0 = LD8(P0, ks + 5); fC1 = LD8(P1, ks + 5);                            \
      fC2 = LD8(P2, ks + 5); fC3 = LD8(P3, ks + 5);                            \
    }                                                                          \
    {                                                                          \
      short8 a0 = AH(30);                                                      \
      acc0 = MFMA_(a0, fA0, acc0); acc1 = MFMA_(a0, fA1, acc1);                \
      acc2 = MFMA_(a0, fA2, acc2); acc3 = MFMA_(a0, fA3, acc3);                \
      short8 a1 = AH(31);                                                      \
      acc0 = MFMA_(a1, fB0, acc0); acc1 = MFMA_(a1, fB1, acc1);                \
      acc2 = MFMA_(a1, fB2, acc2); acc3 = MFMA_(a1, fB3, acc3);                \
      short8 ax = {};  /* ext slice: h_ext = [x, 1, 0...] */                   \
      if (lhi == 0) { ax[0] = (short)f2bf(x_lds[l31]); ax[1] = (short)0x3F80; }\
      acc0 = MFMA_(ax, fC0, acc0); acc1 = MFMA_(ax, fC1, acc1);                \
      acc2 = MFMA_(ax, fC2, acc2); acc3 = MFMA_(ax, fC3, acc3);                \
    }                                                                          \
    NEXTPRO                                                                    \
  }

// 256 blocks x 512 threads (8 waves, 2 waves/SIMD). acc 64 AGPR; arch-VGPR
// live set kept under the empirical 128 cap: 12 frag buffers (48) + cregA 16
// + y 8 + ptrs/temps. Pass-B cell state lives in LDS (private per thread,
// no barriers needed). B-fragments via plain register loads, 3-buffer
// rotation, consume-then-reissue (compiler-managed waits).
__global__ __launch_bounds__(512, 2) void lstm_kernel(
    const float* __restrict__ initial, const float* __restrict__ enc_h,
    const float* __restrict__ enc_c,
    const float* __restrict__ w1, const float* __restrict__ b1,
    const float* __restrict__ w2, const float* __restrict__ b2,
    const u16* __restrict__ wu, float* __restrict__ out) {
  __shared__ __align__(16) unsigned char hbuf[2][TB_ * 1024];   // 64 KB h dbuf
  __shared__ float c_ldsB[TB_][D_ / 2];                          // 32 KB pass-B c
  __shared__ float x_lds[TB_];
  __shared__ float ly1[2][8][TB_];
  __shared__ float ly2[2][8][TB_];

  const int tid = threadIdx.x;
  const int wv  = tid >> 6;
  const int wvu = __builtin_amdgcn_readfirstlane(wv);  // wave-uniform -> SGPR
  const int l   = tid & 63;
  const int l31 = l & 31;
  const int lhi = l >> 5;
  const int b0  = blockIdx.x * TB_;

  // ---- stage initial h (bf16, swizzled) into LDS: 512 threads ----
  {
    int row = tid >> 4;   // 0..31
    int seg = tid & 15;   // 32 cols each
    const float* src = enc_h + (size_t)(b0 + row) * D_ + seg * 32;
#pragma unroll
    for (int jb = 0; jb < 4; ++jb) {
      u16 t[8];
#pragma unroll
      for (int j = 0; j < 8; ++j) t[j] = f2bf(src[jb * 8 + j]);
      int kb = seg * 64 + jb * 16;
      int4 w;
      w.x = t[0] | (t[1] << 16); w.y = t[2] | (t[3] << 16);
      w.z = t[4] | (t[5] << 16); w.w = t[6] | (t[7] << 16);
      *reinterpret_cast<int4*>(&hbuf[0][SWZ(row, kb)]) = w;
    }
  }
  if (tid < TB_) x_lds[tid] = initial[b0 + tid];

  // ---- per-lane step-invariant values (2 passes) ----
  const int colA = wvu * 32 + l31;          // pass 0: n-tile wvu
  const int colB = (8 + wvu) * 32 + l31;    // pass 1: n-tile 8+wvu
  const float w1vA = w1[colA], w1vB = w1[colB];
  const float w2vA = w2[colA], w2vB = w2[colB];
  const float b1v = b1[0], b2v = b2[0];

  float cregA[16];
#pragma unroll
  for (int r = 0; r < 16; ++r) {
    const int row = (r & 3) + 8 * (r >> 2) + 4 * lhi;
    cregA[r] = enc_c[(size_t)(b0 + row) * D_ + colA];
    c_ldsB[row][colB - 256] = enc_c[(size_t)(b0 + row) * D_ + colB];
  }

  // per-lane stream pointers: pass P, gate g -> n-tile g*16 + P*8 + wvu
  const size_t lofs8 = (size_t)l * 8;
  const u16* pA0 = wu + (size_t)(( 0 + wvu) * NU_) * 512 + lofs8;
  const u16* pA1 = wu + (size_t)((16 + wvu) * NU_) * 512 + lofs8;
  const u16* pA2 = wu + (size_t)((32 + wvu) * NU_) * 512 + lofs8;
  const u16* pA3 = wu + (size_t)((48 + wvu) * NU_) * 512 + lofs8;
  const u16* pB0 = wu + (size_t)(( 8 + wvu) * NU_) * 512 + lofs8;
  const u16* pB1 = wu + (size_t)((24 + wvu) * NU_) * 512 + lofs8;
  const u16* pB2 = wu + (size_t)((40 + wvu) * NU_) * 512 + lofs8;
  const u16* pB3 = wu + (size_t)((56 + wvu) * NU_) * 512 + lofs8;
  const int abase = lhi * 16;

  __syncthreads();

  for (int s = 0; s < KS_; ++s) {
    const unsigned char* hr = hbuf[s & 1];
    unsigned char* hw = hbuf[(s & 1) ^ 1];

    short8 fA0, fA1, fA2, fA3, fB0, fB1, fB2, fB3, fC0, fC1, fC2, fC3;
    f32x16 acc0, acc1, acc2, acc3;

    KPRO(pA0, pA1, pA2, pA3)
    KBODY(pA0, pA1, pA2, pA3, KPRO(pB0, pB1, pB2, pB3))
    GATE_REDUCE(cregA[r], cregA[r] = cn, colA, w1vA, w2vA, 0)
    KBODY(pB0, pB1, pB2, pB3, )
    GATE_REDUCE(c_ldsB[row][colB - 256], c_ldsB[row][colB - 256] = cn,
                colB, w1vB, w2vB, 1)

    __syncthreads();  // (1) ly slots + new h complete

    if (tid < TB_) {
      float s1 = b1v, s2 = b2v;
#pragma unroll
      for (int wq = 0; wq < 8; ++wq) {
        s1 += ly1[0][wq][tid] + ly1[1][wq][tid];
        s2 += ly2[0][wq][tid] + ly2[1][wq][tid];
      }
      float y1 = sigm(s1);
      float y2 = (s2 > 0.f) ? s2 : (__expf(s2) - 1.0f);
      out[(size_t)(b0 + tid) * KS_ + s] = y1;
      out[(size_t)B_ * KS_ + (size_t)(b0 + tid) * KS_ + s] = y2;
      x_lds[tid] = y1;
    }
    __syncthreads();  // (2) x + h visible before next step
  }
}

extern "C" void kernel_launch(void* const* d_in, const int* in_sizes, int n_in,
                              void* d_out, int out_size, void* d_ws, size_t ws_size,
                              hipStream_t stream) {
  const float* initial = (const float*)d_in[0];
  const float* enc_h   = (const float*)d_in[1];
  const float* enc_c   = (const float*)d_in[2];
  const float* Wx      = (const float*)d_in[3];
  const float* Wu      = (const float*)d_in[4];
  const float* bias    = (const float*)d_in[5];
  const float* w1      = (const float*)d_in[6];
  const float* b1      = (const float*)d_in[7];
  const float* w2      = (const float*)d_in[8];
  const float* b2      = (const float*)d_in[9];
  u16* pk = (u16*)d_ws;  // 2.06 MB packed [Wu; Wx; b] (bf16, MFMA B-frag order)

  pack_wu_kernel<<<528, 256, 0, stream>>>(Wu, Wx, bias, pk);
  lstm_kernel<<<256, 512, 0, stream>>>(initial, enc_h, enc_c, w1, b1,
                                       w2, b2, pk, (float*)d_out);
}

// Round 14
// 844.867 us; speedup vs baseline: 1.1156x; 1.1156x over previous
//
#include <hip/hip_runtime.h>

#define D_ 512
#define ND_ 2048   // 4*D
#define KS_ 24
#define TB_ 32
#define B_ 8192
#define NU_ 33     // 32 K-units of Wu + 1 ext unit [Wx; b]

typedef __attribute__((ext_vector_type(8))) short short8;
typedef __attribute__((ext_vector_type(16))) float f32x16;
typedef unsigned short u16;

// byte offset into swizzled h tile: row in [0,32), kb = byte offset along d (d*2)
#define SWZ(row, kb) (((row) * 1024) + ((kb) ^ (((row) & 15) << 4)))

__device__ __forceinline__ u16 f2bf(float f) {
  union { float f; unsigned int u; } v; v.f = f;
  unsigned int u = v.u;
  return (u16)((u + 0x7FFFu + ((u >> 16) & 1u)) >> 16);
}

__device__ __forceinline__ float sigm(float x) { return 1.0f / (1.0f + __expf(-x)); }
__device__ __forceinline__ float tanh_(float x) {
  float e = __expf(2.0f * x);
  return (e - 1.0f) / (e + 1.0f);
}

// Pack [Wu; Wx; b] into MFMA B-fragment order, bf16. (unchanged from R8)
__global__ __launch_bounds__(256) void pack_wu_kernel(const float* __restrict__ Wu,
                                                      const float* __restrict__ Wx,
                                                      const float* __restrict__ b,
                                                      u16* __restrict__ pk) {
  int idx = blockIdx.x * 256 + threadIdx.x;
  int lane = idx & 63;
  int unit = idx >> 6;        // 0..2111 = nt*33 + un
  if (unit >= 64 * NU_) return;
  int nt = unit / NU_;
  int un = unit - nt * NU_;
  int col = nt * 32 + (lane & 31);
  u16 t[8] = {0, 0, 0, 0, 0, 0, 0, 0};
  if (un < 32) {
    int k0 = un * 16 + (lane >> 5) * 8;
#pragma unroll
    for (int j = 0; j < 8; ++j) t[j] = f2bf(Wu[(size_t)(k0 + j) * ND_ + col]);
  } else if ((lane >> 5) == 0) {
    t[0] = f2bf(Wx[col]);
    t[1] = f2bf(b[col]);
  }
  int4 w;
  w.x = t[0] | (t[1] << 16); w.y = t[2] | (t[3] << 16);
  w.z = t[4] | (t[5] << 16); w.w = t[6] | (t[7] << 16);
  *reinterpret_cast<int4*>(pk + (size_t)unit * 512 + lane * 8) = w;
}

#define LD8(P, u) (*reinterpret_cast<const short8*>((P) + (size_t)(u) * 512))
#define AH(ks) (*reinterpret_cast<const short8*>(&hr[SWZ(l31, (ks) * 32 + abase)]))
#define MFMA_(A, B, C) __builtin_amdgcn_mfma_f32_32x32x16_bf16(A, B, C, 0, 0, 0)

// prologue: issue K-units 0,1,2 of the 4 gate streams (12 loads, 12 KB/wave)
#define KPRO(P0, P1, P2, P3)                                                   \
    fA0 = LD8(P0, 0); fA1 = LD8(P1, 0); fA2 = LD8(P2, 0); fA3 = LD8(P3, 0);    \
    fB0 = LD8(P0, 1); fB1 = LD8(P1, 1); fB2 = LD8(P2, 1); fB3 = LD8(P3, 1);    \
    fC0 = LD8(P0, 2); fC1 = LD8(P1, 2); fC2 = LD8(P2, 2); fC3 = LD8(P3, 2);

// gate math + per-4-row y-reduction (8 live y scalars). CLOAD/CSTORE are
// expressions over (r, row) giving the cell-state access for this pass.
#define GATE_REDUCE(CLOAD, CSTORE, COL, W1V, W2V, PIDX)                        \
    _Pragma("unroll")                                                          \
    for (int rb = 0; rb < 16; rb += 4) {                                       \
      float y1t[4], y2t[4];                                                    \
      _Pragma("unroll")                                                        \
      for (int q = 0; q < 4; ++q) {                                            \
        const int r = rb + q;                                                  \
        const int row = q + 8 * (rb >> 2) + 4 * lhi;                           \
        float ig = sigm(acc0[r]);                                              \
        float fg = sigm(acc1[r]);                                              \
        float gg = tanh_(acc2[r]);                                             \
        float og = sigm(acc3[r]);                                              \
        float cn = fg * (CLOAD) + ig * gg;                                     \
        CSTORE;                                                                \
        float hn = og * tanh_(cn);                                             \
        *reinterpret_cast<u16*>(&hw[SWZ(row, (COL) * 2)]) = f2bf(hn);          \
        y1t[q] = hn * (W1V);                                                   \
        y2t[q] = hn * (W2V);                                                   \
      }                                                                        \
      _Pragma("unroll")                                                        \
      for (int m = 1; m < 32; m <<= 1) {                                       \
        _Pragma("unroll")                                                      \
        for (int q = 0; q < 4; ++q) {                                          \
          y1t[q] += __shfl_xor(y1t[q], m);                                     \
          y2t[q] += __shfl_xor(y2t[q], m);                                     \
        }                                                                      \
      }                                                                        \
      if (l31 == 0) {                                                          \
        _Pragma("unroll")                                                      \
        for (int q = 0; q < 4; ++q) {                                          \
          const int row = q + 8 * (rb >> 2) + 4 * lhi;                         \
          ly1[PIDX][wvu][row] = y1t[q];                                        \
          ly2[PIDX][wvu][row] = y2t[q];                                        \
        }                                                                      \
      }                                                                        \
    }

// one pass over 33 K-units, 3-buffer rotation, consume-then-reissue: each
// buffer is issued ~2 full iterations before its MFMA consumes it (12 loads
// = 12 KB/wave outstanding). NEXTPRO issues the NEXT pass's (or next step's)
// prologue immediately after the last consume so the loads overlap the gate
// math / reduction / barriers.
#define KBODY(P0, P1, P2, P3, NEXTPRO)                                         \
  {                                                                            \
    acc0 = (f32x16){}; acc1 = (f32x16){}; acc2 = (f32x16){}; acc3 = (f32x16){};\
    _Pragma("unroll 1")                                                        \
    for (int ks = 0; ks < 30; ks += 3) {                                       \
      short8 a0 = AH(ks);                                                      \
      acc0 = MFMA_(a0, fA0, acc0); acc1 = MFMA_(a0, fA1, acc1);                \
      acc2 = MFMA_(a0, fA2, acc2); acc3 = MFMA_(a0, fA3, acc3);                \
      fA0 = LD8(P0, ks + 3); fA1 = LD8(P1, ks + 3);                            \
      fA2 = LD8(P2, ks + 3); fA3 = LD8(P3, ks + 3);                            \
      short8 a1 = AH(ks + 1);                                                  \
      acc0 = MFMA_(a1, fB0, acc0); acc1 = MFMA_(a1, fB1, acc1);                \
      acc2 = MFMA_(a1, fB2, acc2); acc3 = MFMA_(a1, fB3, acc3);                \
      fB0 = LD8(P0, ks + 4); fB1 = LD8(P1, ks + 4);                            \
      fB2 = LD8(P2, ks + 4); fB3 = LD8(P3, ks + 4);                            \
      short8 a2 = AH(ks + 2);                                                  \
      acc0 = MFMA_(a2, fC0, acc0); acc1 = MFMA_(a2, fC1, acc1);                \
      acc2 = MFMA_(a2, fC2, acc2); acc3 = MFMA_(a2, fC3, acc3);                \
      fC0 = LD8(P0, ks + 5); fC1 = LD8(P1, ks + 5);                            \
      fC2 = LD8(P2, ks + 5); fC3 = LD8(P3, ks + 5);                            \
    }                                                                          \
    {                                                                          \
      short8 a0 = AH(30);                                                      \
      acc0 = MFMA_(a0, fA0, acc0); acc1 = MFMA_(a0, fA1, acc1);                \
      acc2 = MFMA_(a0, fA2, acc2); acc3 = MFMA_(a0, fA3, acc3);                \
      short8 a1 = AH(31);                                                      \
      acc0 = MFMA_(a1, fB0, acc0); acc1 = MFMA_(a1, fB1, acc1);                \
      acc2 = MFMA_(a1, fB2, acc2); acc3 = MFMA_(a1, fB3, acc3);                \
      short8 ax = {};  /* ext slice: h_ext = [x, 1, 0...] */                   \
      if (lhi == 0) { ax[0] = (short)f2bf(x_lds[l31]); ax[1] = (short)0x3F80; }\
      acc0 = MFMA_(ax, fC0, acc0); acc1 = MFMA_(ax, fC1, acc1);                \
      acc2 = MFMA_(ax, fC2, acc2); acc3 = MFMA_(ax, fC3, acc3);                \
    }                                                                          \
    NEXTPRO                                                                    \
  }

// 256 blocks x 512 threads (8 waves). NOTE: no min-waves floor in
// launch_bounds — hypothesis is that the ",2" floor made the allocator clamp
// arch VGPRs at the 128 granule and spill (R12/R13); without it the compiler
// can use ~160-200 arch VGPR; usage (~224 unified incl. 64 AGPR) still lands
// in the 256 HW step -> 2 waves/SIMD. 3-deep buffer rotation; pass-B cell
// state in LDS; pass-B tail prefetches NEXT STEP's pass-A units (addresses
// repeat every step) so those 12 loads overlap reduce+barriers+epilogue.
__global__ __launch_bounds__(512) void lstm_kernel(
    const float* __restrict__ initial, const float* __restrict__ enc_h,
    const float* __restrict__ enc_c,
    const float* __restrict__ w1, const float* __restrict__ b1,
    const float* __restrict__ w2, const float* __restrict__ b2,
    const u16* __restrict__ wu, float* __restrict__ out) {
  __shared__ __align__(16) unsigned char hbuf[2][TB_ * 1024];   // 64 KB h dbuf
  __shared__ float c_ldsB[TB_][D_ / 2];                          // 32 KB pass-B c
  __shared__ float x_lds[TB_];
  __shared__ float ly1[2][8][TB_];
  __shared__ float ly2[2][8][TB_];

  const int tid = threadIdx.x;
  const int wv  = tid >> 6;
  const int wvu = __builtin_amdgcn_readfirstlane(wv);  // wave-uniform -> SGPR
  const int l   = tid & 63;
  const int l31 = l & 31;
  const int lhi = l >> 5;
  const int b0  = blockIdx.x * TB_;

  // ---- stage initial h (bf16, swizzled) into LDS: 512 threads ----
  {
    int row = tid >> 4;   // 0..31
    int seg = tid & 15;   // 32 cols each
    const float* src = enc_h + (size_t)(b0 + row) * D_ + seg * 32;
#pragma unroll
    for (int jb = 0; jb < 4; ++jb) {
      u16 t[8];
#pragma unroll
      for (int j = 0; j < 8; ++j) t[j] = f2bf(src[jb * 8 + j]);
      int kb = seg * 64 + jb * 16;
      int4 w;
      w.x = t[0] | (t[1] << 16); w.y = t[2] | (t[3] << 16);
      w.z = t[4] | (t[5] << 16); w.w = t[6] | (t[7] << 16);
      *reinterpret_cast<int4*>(&hbuf[0][SWZ(row, kb)]) = w;
    }
  }
  if (tid < TB_) x_lds[tid] = initial[b0 + tid];

  // ---- per-lane step-invariant values (2 passes) ----
  const int colA = wvu * 32 + l31;          // pass 0: n-tile wvu
  const int colB = (8 + wvu) * 32 + l31;    // pass 1: n-tile 8+wvu
  const float w1vA = w1[colA], w1vB = w1[colB];
  const float w2vA = w2[colA], w2vB = w2[colB];
  const float b1v = b1[0], b2v = b2[0];

  float cregA[16];
#pragma unroll
  for (int r = 0; r < 16; ++r) {
    const int row = (r & 3) + 8 * (r >> 2) + 4 * lhi;
    cregA[r] = enc_c[(size_t)(b0 + row) * D_ + colA];
    c_ldsB[row][colB - 256] = enc_c[(size_t)(b0 + row) * D_ + colB];
  }

  // per-lane stream pointers: pass P, gate g -> n-tile g*16 + P*8 + wvu
  const size_t lofs8 = (size_t)l * 8;
  const u16* pA0 = wu + (size_t)(( 0 + wvu) * NU_) * 512 + lofs8;
  const u16* pA1 = wu + (size_t)((16 + wvu) * NU_) * 512 + lofs8;
  const u16* pA2 = wu + (size_t)((32 + wvu) * NU_) * 512 + lofs8;
  const u16* pA3 = wu + (size_t)((48 + wvu) * NU_) * 512 + lofs8;
  const u16* pB0 = wu + (size_t)(( 8 + wvu) * NU_) * 512 + lofs8;
  const u16* pB1 = wu + (size_t)((24 + wvu) * NU_) * 512 + lofs8;
  const u16* pB2 = wu + (size_t)((40 + wvu) * NU_) * 512 + lofs8;
  const u16* pB3 = wu + (size_t)((56 + wvu) * NU_) * 512 + lofs8;
  const int abase = lhi * 16;

  __syncthreads();

  short8 fA0, fA1, fA2, fA3, fB0, fB1, fB2, fB3, fC0, fC1, fC2, fC3;
  f32x16 acc0, acc1, acc2, acc3;

  KPRO(pA0, pA1, pA2, pA3)   // first step's pass-A prologue

  for (int s = 0; s < KS_; ++s) {
    const unsigned char* hr = hbuf[s & 1];
    unsigned char* hw = hbuf[(s & 1) ^ 1];

    KBODY(pA0, pA1, pA2, pA3, KPRO(pB0, pB1, pB2, pB3))
    GATE_REDUCE(cregA[r], cregA[r] = cn, colA, w1vA, w2vA, 0)
    // pass-B body; tail issues NEXT STEP's pass-A prologue (same addresses)
    KBODY(pB0, pB1, pB2, pB3, KPRO(pA0, pA1, pA2, pA3))
    GATE_REDUCE(c_ldsB[row][colB - 256], c_ldsB[row][colB - 256] = cn,
                colB, w1vB, w2vB, 1)

    __syncthreads();  // (1) ly slots + new h complete

    if (tid < TB_) {
      float s1 = b1v, s2 = b2v;
#pragma unroll
      for (int wq = 0; wq < 8; ++wq) {
        s1 += ly1[0][wq][tid] + ly1[1][wq][tid];
        s2 += ly2[0][wq][tid] + ly2[1][wq][tid];
      }
      float y1 = sigm(s1);
      float y2 = (s2 > 0.f) ? s2 : (__expf(s2) - 1.0f);
      out[(size_t)(b0 + tid) * KS_ + s] = y1;
      out[(size_t)B_ * KS_ + (size_t)(b0 + tid) * KS_ + s] = y2;
      x_lds[tid] = y1;
    }
    __syncthreads();  // (2) x + h visible before next step
  }
}

extern "C" void kernel_launch(void* const* d_in, const int* in_sizes, int n_in,
                              void* d_out, int out_size, void* d_ws, size_t ws_size,
                              hipStream_t stream) {
  const float* initial = (const float*)d_in[0];
  const float* enc_h   = (const float*)d_in[1];
  const float* enc_c   = (const float*)d_in[2];
  const float* Wx      = (const float*)d_in[3];
  const float* Wu      = (const float*)d_in[4];
  const float* bias    = (const float*)d_in[5];
  const float* w1      = (const float*)d_in[6];
  const float* b1      = (const float*)d_in[7];
  const float* w2      = (const float*)d_in[8];
  const float* b2      = (const float*)d_in[9];
  u16* pk = (u16*)d_ws;  // 2.06 MB packed [Wu; Wx; b] (bf16, MFMA B-frag order)

  pack_wu_kernel<<<528, 256, 0, stream>>>(Wu, Wx, bias, pk);
  lstm_kernel<<<256, 512, 0, stream>>>(initial, enc_h, enc_c, w1, b1,
                                       w2, b2, pk, (float*)d_out);
}

// Round 15
// 836.398 us; speedup vs baseline: 1.1269x; 1.0101x over previous
//
#include <hip/hip_runtime.h>

#define D_ 512
#define ND_ 2048   // 4*D
#define KS_ 24
#define TB_ 32
#define B_ 8192
#define NU_ 33     // 32 K-units of Wu + 1 ext unit [Wx; b]

typedef __attribute__((ext_vector_type(8))) short short8;
typedef __attribute__((ext_vector_type(16))) float f32x16;
typedef unsigned short u16;

// byte offset into swizzled h tile: row in [0,32), kb = byte offset along d (d*2)
#define SWZ(row, kb) (((row) * 1024) + ((kb) ^ (((row) & 15) << 4)))

__device__ __forceinline__ u16 f2bf(float f) {
  union { float f; unsigned int u; } v; v.f = f;
  unsigned int u = v.u;
  return (u16)((u + 0x7FFFu + ((u >> 16) & 1u)) >> 16);
}

__device__ __forceinline__ float sigm(float x) { return 1.0f / (1.0f + __expf(-x)); }
__device__ __forceinline__ float tanh_(float x) {
  float e = __expf(2.0f * x);
  return (e - 1.0f) / (e + 1.0f);
}

// Pack [Wu; Wx; b] into MFMA B-fragment order, bf16. (unchanged from R8)
__global__ __launch_bounds__(256) void pack_wu_kernel(const float* __restrict__ Wu,
                                                      const float* __restrict__ Wx,
                                                      const float* __restrict__ b,
                                                      u16* __restrict__ pk) {
  int idx = blockIdx.x * 256 + threadIdx.x;
  int lane = idx & 63;
  int unit = idx >> 6;        // 0..2111 = nt*33 + un
  if (unit >= 64 * NU_) return;
  int nt = unit / NU_;
  int un = unit - nt * NU_;
  int col = nt * 32 + (lane & 31);
  u16 t[8] = {0, 0, 0, 0, 0, 0, 0, 0};
  if (un < 32) {
    int k0 = un * 16 + (lane >> 5) * 8;
#pragma unroll
    for (int j = 0; j < 8; ++j) t[j] = f2bf(Wu[(size_t)(k0 + j) * ND_ + col]);
  } else if ((lane >> 5) == 0) {
    t[0] = f2bf(Wx[col]);
    t[1] = f2bf(b[col]);
  }
  int4 w;
  w.x = t[0] | (t[1] << 16); w.y = t[2] | (t[3] << 16);
  w.z = t[4] | (t[5] << 16); w.w = t[6] | (t[7] << 16);
  *reinterpret_cast<int4*>(pk + (size_t)unit * 512 + lane * 8) = w;
}

#define LD8(P, u) (*reinterpret_cast<const short8*>((P) + (size_t)(u) * 512))
#define AH(ks) (*reinterpret_cast<const short8*>(&hr[SWZ(l31, (ks) * 32 + abase)]))
#define MFMA_(A, B, C) __builtin_amdgcn_mfma_f32_32x32x16_bf16(A, B, C, 0, 0, 0)

// prologue: issue K-units 0,1 of the 4 gate streams (8 loads, 8 KB/wave)
#define KPRO(P0, P1, P2, P3)                                                   \
    fA0 = LD8(P0, 0); fA1 = LD8(P1, 0); fA2 = LD8(P2, 0); fA3 = LD8(P3, 0);    \
    fB0 = LD8(P0, 1); fB1 = LD8(P1, 1); fB2 = LD8(P2, 1); fB3 = LD8(P3, 1);

// gate math + per-4-row y-reduction (8 live y scalars). CLOAD/CSTORE are
// expressions over (r, row) giving the cell-state access for this pass.
#define GATE_REDUCE(CLOAD, CSTORE, COL, W1V, W2V, PIDX)                        \
    _Pragma("unroll")                                                          \
    for (int rb = 0; rb < 16; rb += 4) {                                       \
      float y1t[4], y2t[4];                                                    \
      _Pragma("unroll")                                                        \
      for (int q = 0; q < 4; ++q) {                                            \
        const int r = rb + q;                                                  \
        const int row = q + 8 * (rb >> 2) + 4 * lhi;                           \
        float ig = sigm(acc0[r]);                                              \
        float fg = sigm(acc1[r]);                                              \
        float gg = tanh_(acc2[r]);                                             \
        float og = sigm(acc3[r]);                                              \
        float cn = fg * (CLOAD) + ig * gg;                                     \
        CSTORE;                                                                \
        float hn = og * tanh_(cn);                                             \
        *reinterpret_cast<u16*>(&hw[SWZ(row, (COL) * 2)]) = f2bf(hn);          \
        y1t[q] = hn * (W1V);                                                   \
        y2t[q] = hn * (W2V);                                                   \
      }                                                                        \
      _Pragma("unroll")                                                        \
      for (int m = 1; m < 32; m <<= 1) {                                       \
        _Pragma("unroll")                                                      \
        for (int q = 0; q < 4; ++q) {                                          \
          y1t[q] += __shfl_xor(y1t[q], m);                                     \
          y2t[q] += __shfl_xor(y2t[q], m);                                     \
        }                                                                      \
      }                                                                        \
      if (l31 == 0) {                                                          \
        _Pragma("unroll")                                                      \
        for (int q = 0; q < 4; ++q) {                                          \
          const int row = q + 8 * (rb >> 2) + 4 * lhi;                         \
          ly1[PIDX][wvu][row] = y1t[q];                                        \
          ly2[PIDX][wvu][row] = y2t[q];                                        \
        }                                                                      \
      }                                                                        \
    }

// one pass over 33 K-units, 2-deep ping-pong (8 buffers — fits the 128-VGPR
// allocator clamp; 12 buffers spill, proven R12-R14). NEXTPRO issues the
// next pass's (or next step's) first 2 units right after the last consume,
// so those 8 loads get the whole gate/reduce phase (~1000 cyc) of lead.
#define KBODY(P0, P1, P2, P3, NEXTPRO)                                         \
  {                                                                            \
    acc0 = (f32x16){}; acc1 = (f32x16){}; acc2 = (f32x16){}; acc3 = (f32x16){};\
    _Pragma("unroll 1")                                                        \
    for (int ks = 0; ks < 30; ks += 2) {                                       \
      short8 a0 = AH(ks);                                                      \
      acc0 = MFMA_(a0, fA0, acc0); acc1 = MFMA_(a0, fA1, acc1);                \
      acc2 = MFMA_(a0, fA2, acc2); acc3 = MFMA_(a0, fA3, acc3);                \
      fA0 = LD8(P0, ks + 2); fA1 = LD8(P1, ks + 2);                            \
      fA2 = LD8(P2, ks + 2); fA3 = LD8(P3, ks + 2);                            \
      short8 a1 = AH(ks + 1);                                                  \
      acc0 = MFMA_(a1, fB0, acc0); acc1 = MFMA_(a1, fB1, acc1);                \
      acc2 = MFMA_(a1, fB2, acc2); acc3 = MFMA_(a1, fB3, acc3);                \
      fB0 = LD8(P0, ks + 3); fB1 = LD8(P1, ks + 3);                            \
      fB2 = LD8(P2, ks + 3); fB3 = LD8(P3, ks + 3);                            \
    }                                                                          \
    {                                                                          \
      short8 a0 = AH(30);   /* consume unit 30 (in fA) */                      \
      acc0 = MFMA_(a0, fA0, acc0); acc1 = MFMA_(a0, fA1, acc1);                \
      acc2 = MFMA_(a0, fA2, acc2); acc3 = MFMA_(a0, fA3, acc3);                \
      fA0 = LD8(P0, 32); fA1 = LD8(P1, 32);  /* ext unit */                    \
      fA2 = LD8(P2, 32); fA3 = LD8(P3, 32);                                    \
      short8 a1 = AH(31);   /* consume unit 31 (in fB) */                      \
      acc0 = MFMA_(a1, fB0, acc0); acc1 = MFMA_(a1, fB1, acc1);                \
      acc2 = MFMA_(a1, fB2, acc2); acc3 = MFMA_(a1, fB3, acc3);                \
      short8 ax = {};  /* ext slice: h_ext = [x, 1, 0...] */                   \
      if (lhi == 0) { ax[0] = (short)f2bf(x_lds[l31]); ax[1] = (short)0x3F80; }\
      acc0 = MFMA_(ax, fA0, acc0); acc1 = MFMA_(ax, fA1, acc1);                \
      acc2 = MFMA_(ax, fA2, acc2); acc3 = MFMA_(ax, fA3, acc3);                \
    }                                                                          \
    NEXTPRO                                                                    \
  }

// 256 blocks x 512 threads (8 waves, 2 waves/SIMD). 2-deep ping-pong (the
// only spill-free high-rate config, R11) + cross-phase hoisted prologues:
// pass-A tail issues pass-B units 0,1; pass-B tail issues NEXT STEP's pass-A
// units (addresses repeat every step) — 8 loads overlap each gate/reduce
// phase and the barriers. Pass-B cell state in LDS (saves 16 regs).
__global__ __launch_bounds__(512) void lstm_kernel(
    const float* __restrict__ initial, const float* __restrict__ enc_h,
    const float* __restrict__ enc_c,
    const float* __restrict__ w1, const float* __restrict__ b1,
    const float* __restrict__ w2, const float* __restrict__ b2,
    const u16* __restrict__ wu, float* __restrict__ out) {
  __shared__ __align__(16) unsigned char hbuf[2][TB_ * 1024];   // 64 KB h dbuf
  __shared__ float c_ldsB[TB_][D_ / 2];                          // 32 KB pass-B c
  __shared__ float x_lds[TB_];
  __shared__ float ly1[2][8][TB_];
  __shared__ float ly2[2][8][TB_];

  const int tid = threadIdx.x;
  const int wv  = tid >> 6;
  const int wvu = __builtin_amdgcn_readfirstlane(wv);  // wave-uniform -> SGPR
  const int l   = tid & 63;
  const int l31 = l & 31;
  const int lhi = l >> 5;
  const int b0  = blockIdx.x * TB_;

  // ---- stage initial h (bf16, swizzled) into LDS: 512 threads ----
  {
    int row = tid >> 4;   // 0..31
    int seg = tid & 15;   // 32 cols each
    const float* src = enc_h + (size_t)(b0 + row) * D_ + seg * 32;
#pragma unroll
    for (int jb = 0; jb < 4; ++jb) {
      u16 t[8];
#pragma unroll
      for (int j = 0; j < 8; ++j) t[j] = f2bf(src[jb * 8 + j]);
      int kb = seg * 64 + jb * 16;
      int4 w;
      w.x = t[0] | (t[1] << 16); w.y = t[2] | (t[3] << 16);
      w.z = t[4] | (t[5] << 16); w.w = t[6] | (t[7] << 16);
      *reinterpret_cast<int4*>(&hbuf[0][SWZ(row, kb)]) = w;
    }
  }
  if (tid < TB_) x_lds[tid] = initial[b0 + tid];

  // ---- per-lane step-invariant values (2 passes) ----
  const int colA = wvu * 32 + l31;          // pass 0: n-tile wvu
  const int colB = (8 + wvu) * 32 + l31;    // pass 1: n-tile 8+wvu
  const float w1vA = w1[colA], w1vB = w1[colB];
  const float w2vA = w2[colA], w2vB = w2[colB];
  const float b1v = b1[0], b2v = b2[0];

  float cregA[16];
#pragma unroll
  for (int r = 0; r < 16; ++r) {
    const int row = (r & 3) + 8 * (r >> 2) + 4 * lhi;
    cregA[r] = enc_c[(size_t)(b0 + row) * D_ + colA];
    c_ldsB[row][colB - 256] = enc_c[(size_t)(b0 + row) * D_ + colB];
  }

  // per-lane stream pointers: pass P, gate g -> n-tile g*16 + P*8 + wvu
  const size_t lofs8 = (size_t)l * 8;
  const u16* pA0 = wu + (size_t)(( 0 + wvu) * NU_) * 512 + lofs8;
  const u16* pA1 = wu + (size_t)((16 + wvu) * NU_) * 512 + lofs8;
  const u16* pA2 = wu + (size_t)((32 + wvu) * NU_) * 512 + lofs8;
  const u16* pA3 = wu + (size_t)((48 + wvu) * NU_) * 512 + lofs8;
  const u16* pB0 = wu + (size_t)(( 8 + wvu) * NU_) * 512 + lofs8;
  const u16* pB1 = wu + (size_t)((24 + wvu) * NU_) * 512 + lofs8;
  const u16* pB2 = wu + (size_t)((40 + wvu) * NU_) * 512 + lofs8;
  const u16* pB3 = wu + (size_t)((56 + wvu) * NU_) * 512 + lofs8;
  const int abase = lhi * 16;

  __syncthreads();

  short8 fA0, fA1, fA2, fA3, fB0, fB1, fB2, fB3;
  f32x16 acc0, acc1, acc2, acc3;

  KPRO(pA0, pA1, pA2, pA3)   // first step's pass-A prologue

  for (int s = 0; s < KS_; ++s) {
    const unsigned char* hr = hbuf[s & 1];
    unsigned char* hw = hbuf[(s & 1) ^ 1];

    KBODY(pA0, pA1, pA2, pA3, KPRO(pB0, pB1, pB2, pB3))
    GATE_REDUCE(cregA[r], cregA[r] = cn, colA, w1vA, w2vA, 0)
    // pass-B body; tail issues NEXT STEP's pass-A prologue (same addresses)
    KBODY(pB0, pB1, pB2, pB3, KPRO(pA0, pA1, pA2, pA3))
    GATE_REDUCE(c_ldsB[row][colB - 256], c_ldsB[row][colB - 256] = cn,
                colB, w1vB, w2vB, 1)

    __syncthreads();  // (1) ly slots + new h complete

    if (tid < TB_) {
      float s1 = b1v, s2 = b2v;
#pragma unroll
      for (int wq = 0; wq < 8; ++wq) {
        s1 += ly1[0][wq][tid] + ly1[1][wq][tid];
        s2 += ly2[0][wq][tid] + ly2[1][wq][tid];
      }
      float y1 = sigm(s1);
      float y2 = (s2 > 0.f) ? s2 : (__expf(s2) - 1.0f);
      out[(size_t)(b0 + tid) * KS_ + s] = y1;
      out[(size_t)B_ * KS_ + (size_t)(b0 + tid) * KS_ + s] = y2;
      x_lds[tid] = y1;
    }
    __syncthreads();  // (2) x + h visible before next step
  }
}

extern "C" void kernel_launch(void* const* d_in, const int* in_sizes, int n_in,
                              void* d_out, int out_size, void* d_ws, size_t ws_size,
                              hipStream_t stream) {
  const float* initial = (const float*)d_in[0];
  const float* enc_h   = (const float*)d_in[1];
  const float* enc_c   = (const float*)d_in[2];
  const float* Wx      = (const float*)d_in[3];
  const float* Wu      = (const float*)d_in[4];
  const float* bias    = (const float*)d_in[5];
  const float* w1      = (const float*)d_in[6];
  const float* b1      = (const float*)d_in[7];
  const float* w2      = (const float*)d_in[8];
  const float* b2      = (const float*)d_in[9];
  u16* pk = (u16*)d_ws;  // 2.06 MB packed [Wu; Wx; b] (bf16, MFMA B-frag order)

  pack_wu_kernel<<<528, 256, 0, stream>>>(Wu, Wx, bias, pk);
  lstm_kernel<<<256, 512, 0, stream>>>(initial, enc_h, enc_c, w1, b1,
                                       w2, b2, pk, (float*)d_out);
}

// Round 16
// 809.718 us; speedup vs baseline: 1.1641x; 1.0329x over previous
//
#include <hip/hip_runtime.h>

#define D_ 512
#define ND_ 2048   // 4*D
#define KS_ 24
#define TB_ 32
#define B_ 8192
#define NUI_ 16    // int8 K-units per n-tile (K=32 each), 1 KB per unit

typedef __attribute__((ext_vector_type(4))) int i32x4;
typedef __attribute__((ext_vector_type(16))) int i32x16;

// byte offset into swizzled int8 h tile: row in [0,32), kb = byte offset (1B/elem)
#define SWZ8(row, kb) (((row) * 512) + ((kb) ^ (((row) & 15) << 4)))

__device__ __forceinline__ float sigm(float x) { return 1.0f / (1.0f + __expf(-x)); }
__device__ __forceinline__ float tanh_(float x) {
  float e = __expf(2.0f * x);
  return (e - 1.0f) / (e + 1.0f);
}

// per-output-column scale: sw[n] = max_k |Wu[k][n]| / 127
__global__ __launch_bounds__(256) void colscale_kernel(const float* __restrict__ Wu,
                                                       float* __restrict__ sw) {
  int n = blockIdx.x * 256 + threadIdx.x;   // grid 8 -> 2048
  float m = 0.f;
  for (int k = 0; k < D_; ++k) m = fmaxf(m, fabsf(Wu[(size_t)k * ND_ + n]));
  sw[n] = fmaxf(m, 1e-12f) * (1.0f / 127.0f);
}

// Pack Wu -> int8 MFMA B-frag order for mfma_i32_32x32x32_i8.
// Unit (nt, ku): lane l, elem e  <->  B[k = ku*32 + 16*(l>>5) + e][n = nt*32 + (l&31)]
// (same lane-half-contiguous-K pattern as the verified bf16 32x32x16 layout, 16 elems)
__global__ __launch_bounds__(256) void pack_i8_kernel(const float* __restrict__ Wu,
                                                      const float* __restrict__ sw,
                                                      signed char* __restrict__ pk) {
  int idx = blockIdx.x * 256 + threadIdx.x;   // 1024 units * 64 lanes = 65536
  int lane = idx & 63;
  int unit = idx >> 6;            // nt*16 + ku
  int nt = unit >> 4, ku = unit & 15;
  int n  = nt * 32 + (lane & 31);
  int k0 = ku * 32 + (lane >> 5) * 16;
  float inv = 1.0f / sw[n];       // = 127/colmax
  unsigned w[4] = {0, 0, 0, 0};
#pragma unroll
  for (int e = 0; e < 16; ++e) {
    float v = rintf(Wu[(size_t)(k0 + e) * ND_ + n] * inv);
    v = fminf(fmaxf(v, -127.f), 127.f);
    int qi = (int)v;
    w[e >> 2] |= (unsigned)(qi & 255) << ((e & 3) * 8);
  }
  i32x4 q = {(int)w[0], (int)w[1], (int)w[2], (int)w[3]};
  *reinterpret_cast<i32x4*>(pk + (size_t)unit * 1024 + lane * 16) = q;
}

#define LDU(S, u) (*reinterpret_cast<const i32x4*>((S) + (size_t)(u) * 1024 + lofs16))
#define AH8(ku_) (*reinterpret_cast<const i8x4c*>(&hr[SWZ8(l31, (ku_) * 32 + abase)]))
#define MFMAI(A, B, C) __builtin_amdgcn_mfma_i32_32x32x32_i8(A, B, C, 0, 0, 0)
typedef const i32x4 i8x4c;

// one pass = 16 K-units for one n-tile per gate, 2-deep register ping-pong
// (R11's proven spill-free codegen shape, half the iterations).
#define KSTEP_I8(S0, S1, S2, S3)                                               \
  {                                                                            \
    acc0 = (i32x16){}; acc1 = (i32x16){}; acc2 = (i32x16){}; acc3 = (i32x16){};\
    i32x4 fA0 = LDU(S0, 0), fA1 = LDU(S1, 0), fA2 = LDU(S2, 0), fA3 = LDU(S3, 0);\
    i32x4 fB0, fB1, fB2, fB3;                                                  \
    _Pragma("unroll 1")                                                        \
    for (int ku = 0; ku < 14; ku += 2) {                                       \
      fB0 = LDU(S0, ku + 1); fB1 = LDU(S1, ku + 1);                            \
      fB2 = LDU(S2, ku + 1); fB3 = LDU(S3, ku + 1);                            \
      i32x4 a0 = AH8(ku);                                                      \
      acc0 = MFMAI(a0, fA0, acc0); acc1 = MFMAI(a0, fA1, acc1);                \
      acc2 = MFMAI(a0, fA2, acc2); acc3 = MFMAI(a0, fA3, acc3);                \
      fA0 = LDU(S0, ku + 2); fA1 = LDU(S1, ku + 2);                            \
      fA2 = LDU(S2, ku + 2); fA3 = LDU(S3, ku + 2);                            \
      i32x4 a1 = AH8(ku + 1);                                                  \
      acc0 = MFMAI(a1, fB0, acc0); acc1 = MFMAI(a1, fB1, acc1);                \
      acc2 = MFMAI(a1, fB2, acc2); acc3 = MFMAI(a1, fB3, acc3);                \
    }                                                                          \
    {                                                                          \
      fB0 = LDU(S0, 15); fB1 = LDU(S1, 15);                                    \
      fB2 = LDU(S2, 15); fB3 = LDU(S3, 15);                                    \
      i32x4 a0 = AH8(14);                                                      \
      acc0 = MFMAI(a0, fA0, acc0); acc1 = MFMAI(a0, fA1, acc1);                \
      acc2 = MFMAI(a0, fA2, acc2); acc3 = MFMAI(a0, fA3, acc3);                \
      i32x4 a1 = AH8(15);                                                      \
      acc0 = MFMAI(a1, fB0, acc0); acc1 = MFMAI(a1, fB1, acc1);                \
      acc2 = MFMAI(a1, fB2, acc2); acc3 = MFMAI(a1, fB3, acc3);                \
    }                                                                          \
  }

// gate math + y accumulation for one pass; z = sw*acc + x*wx + bb (VALU ext)
#define GATEPH(CREG, COL, W1V, W2V)                                            \
  {                                                                            \
    const float swi = sw_l[COL],        swf = sw_l[512 + COL];                 \
    const float swg = sw_l[1024 + COL], swo = sw_l[1536 + COL];                \
    const float wxi = wx_l[COL],        wxf = wx_l[512 + COL];                 \
    const float wxg = wx_l[1024 + COL], wxo = wx_l[1536 + COL];                \
    const float bbi = bb_l[COL],        bbf = bb_l[512 + COL];                 \
    const float bbg = bb_l[1024 + COL], bbo = bb_l[1536 + COL];                \
    _Pragma("unroll")                                                          \
    for (int r = 0; r < 16; ++r) {                                             \
      const int row = (r & 3) + 8 * (r >> 2) + 4 * lhi;                        \
      const float xv = x_lds[row];                                             \
      float zi = swi * (float)acc0[r] + xv * wxi + bbi;                        \
      float zf = swf * (float)acc1[r] + xv * wxf + bbf;                        \
      float zg = swg * (float)acc2[r] + xv * wxg + bbg;                        \
      float zo = swo * (float)acc3[r] + xv * wxo + bbo;                        \
      float ig = sigm(zi);                                                     \
      float fg = sigm(zf);                                                     \
      float gg = tanh_(zg);                                                    \
      float og = sigm(zo);                                                     \
      float cn = fg * CREG[r] + ig * gg;                                       \
      CREG[r] = cn;                                                            \
      float hn = og * tanh_(cn);                                               \
      hw[SWZ8(row, COL)] = (signed char)__float2int_rn(hn * 127.0f);           \
      y1p[r] += hn * (W1V);                                                    \
      y2p[r] += hn * (W2V);                                                    \
    }                                                                          \
  }

// 256 blocks x 512 threads (8 waves, 2 waves/SIMD). R11 skeleton with int8
// Wu (1.05 MB/step vs 2.11 bf16) and int8 h in LDS (fixed 1/127 scale — h is
// strictly bounded by sigm*tanh). x*Wx+b in VALU with constants from LDS.
__global__ __launch_bounds__(512) void lstm_kernel(
    const float* __restrict__ initial, const float* __restrict__ enc_h,
    const float* __restrict__ enc_c, const float* __restrict__ Wx,
    const float* __restrict__ bias,
    const float* __restrict__ w1, const float* __restrict__ b1,
    const float* __restrict__ w2, const float* __restrict__ b2,
    const signed char* __restrict__ pk, const float* __restrict__ swg_,
    float* __restrict__ out) {
  __shared__ __align__(16) signed char hbuf[2][TB_ * 512];   // 32 KB int8 h dbuf
  __shared__ float sw_l[ND_];   // 8 KB  z-scale (colmax/127/127)
  __shared__ float wx_l[ND_];   // 8 KB
  __shared__ float bb_l[ND_];   // 8 KB
  __shared__ float x_lds[TB_];
  __shared__ float ly1[8][TB_];
  __shared__ float ly2[8][TB_];
  __shared__ float ystg[2][TB_][KS_];   // 6 KB coalesced out staging

  const int tid = threadIdx.x;
  const int wv  = tid >> 6;
  const int wvu = __builtin_amdgcn_readfirstlane(wv);
  const int l   = tid & 63;
  const int l31 = l & 31;
  const int lhi = l >> 5;
  const int b0  = blockIdx.x * TB_;

  // ---- stage tables: sw (incl /127 h-scale), wx, bb ----
#pragma unroll
  for (int j = 0; j < 4; ++j) {
    int n = tid + 512 * j;
    sw_l[n] = swg_[n] * (1.0f / 127.0f);
    wx_l[n] = Wx[n];
    bb_l[n] = bias[n];
  }

  // ---- stage initial h (int8, swizzled): thread = (row, 32-col segment) ----
  {
    int row = tid >> 4;   // 0..31
    int seg = tid & 15;   // 32 cols each
    const float* src = enc_h + (size_t)(b0 + row) * D_ + seg * 32;
    const int m = (row & 15) << 4;
#pragma unroll
    for (int half = 0; half < 2; ++half) {
      unsigned w[4] = {0, 0, 0, 0};
#pragma unroll
      for (int i = 0; i < 16; ++i) {
        float v = rintf(src[half * 16 + i] * 127.0f);
        v = fminf(fmaxf(v, -127.f), 127.f);
        w[i >> 2] |= (unsigned)((int)v & 255) << ((i & 3) * 8);
      }
      i32x4 q = {(int)w[0], (int)w[1], (int)w[2], (int)w[3]};
      int addr = row * 512 + ((seg * 32 + half * 16) ^ m);
      *reinterpret_cast<i32x4*>(&hbuf[0][addr]) = q;
    }
  }
  if (tid < TB_) x_lds[tid] = initial[b0 + tid];

  // ---- per-lane step-invariant values (2 passes) ----
  const int colA = wvu * 32 + l31;          // pass 0: h/c col in [0,256)
  const int colB = 256 + colA;              // pass 1
  const float w1vA = w1[colA], w1vB = w1[colB];
  const float w2vA = w2[colA], w2vB = w2[colB];
  const float b1v = b1[0], b2v = b2[0];

  float cregA[16], cregB[16];
#pragma unroll
  for (int r = 0; r < 16; ++r) {
    const int row = (r & 3) + 8 * (r >> 2) + 4 * lhi;
    cregA[r] = enc_c[(size_t)(b0 + row) * D_ + colA];
    cregB[r] = enc_c[(size_t)(b0 + row) * D_ + colB];
  }

  // wave-uniform stream bases (SGPR): pass P, gate g -> n-tile g*16 + P*8 + wvu
  const signed char* sA0 = pk + (size_t)(( 0 + wvu) * NUI_) * 1024;
  const signed char* sA1 = pk + (size_t)((16 + wvu) * NUI_) * 1024;
  const signed char* sA2 = pk + (size_t)((32 + wvu) * NUI_) * 1024;
  const signed char* sA3 = pk + (size_t)((48 + wvu) * NUI_) * 1024;
  const signed char* sB0 = pk + (size_t)(( 8 + wvu) * NUI_) * 1024;
  const signed char* sB1 = pk + (size_t)((24 + wvu) * NUI_) * 1024;
  const signed char* sB2 = pk + (size_t)((40 + wvu) * NUI_) * 1024;
  const signed char* sB3 = pk + (size_t)((56 + wvu) * NUI_) * 1024;
  const size_t lofs16 = (size_t)l * 16;
  const int abase = lhi * 16;

  __syncthreads();

  for (int s = 0; s < KS_; ++s) {
    const signed char* hr = hbuf[s & 1];
    signed char* hw = hbuf[(s & 1) ^ 1];

    float y1p[16], y2p[16];
#pragma unroll
    for (int r = 0; r < 16; ++r) { y1p[r] = 0.f; y2p[r] = 0.f; }

    i32x16 acc0, acc1, acc2, acc3;
    KSTEP_I8(sA0, sA1, sA2, sA3)
    GATEPH(cregA, colA, w1vA, w2vA)
    KSTEP_I8(sB0, sB1, sB2, sB3)
    GATEPH(cregB, colB, w1vB, w2vB)

    // reduce y partials across the 32 lanes of each half-wave
#pragma unroll
    for (int m = 1; m < 32; m <<= 1) {
#pragma unroll
      for (int r = 0; r < 16; ++r) {
        y1p[r] += __shfl_xor(y1p[r], m);
        y2p[r] += __shfl_xor(y2p[r], m);
      }
    }
    if (l31 == 0) {
#pragma unroll
      for (int r = 0; r < 16; ++r) {
        const int row = (r & 3) + 8 * (r >> 2) + 4 * lhi;
        ly1[wvu][row] = y1p[r];
        ly2[wvu][row] = y2p[r];
      }
    }
    __syncthreads();  // (1) ly slots + new h complete

    if (tid < TB_) {
      float s1 = b1v, s2 = b2v;
#pragma unroll
      for (int wq = 0; wq < 8; ++wq) { s1 += ly1[wq][tid]; s2 += ly2[wq][tid]; }
      float y1 = sigm(s1);
      float y2 = (s2 > 0.f) ? s2 : (__expf(s2) - 1.0f);
      ystg[0][tid][s] = y1;
      ystg[1][tid][s] = y2;
      x_lds[tid] = y1;
    }
    __syncthreads();  // (2) x + h visible before next step
  }

  // coalesced out flush: 2 * 32 * 24 = 1536 floats
  for (int i = tid; i < 2 * TB_ * KS_; i += 512) {
    int which = i / (TB_ * KS_);
    int rem = i - which * (TB_ * KS_);
    int row = rem / KS_;
    int k = rem - row * KS_;
    out[(size_t)which * B_ * KS_ + (size_t)(b0 + row) * KS_ + k] = ystg[which][row][k];
  }
}

extern "C" void kernel_launch(void* const* d_in, const int* in_sizes, int n_in,
                              void* d_out, int out_size, void* d_ws, size_t ws_size,
                              hipStream_t stream) {
  const float* initial = (const float*)d_in[0];
  const float* enc_h   = (const float*)d_in[1];
  const float* enc_c   = (const float*)d_in[2];
  const float* Wx      = (const float*)d_in[3];
  const float* Wu      = (const float*)d_in[4];
  const float* bias    = (const float*)d_in[5];
  const float* w1      = (const float*)d_in[6];
  const float* b1      = (const float*)d_in[7];
  const float* w2      = (const float*)d_in[8];
  const float* b2      = (const float*)d_in[9];
  signed char* pk = (signed char*)d_ws;                      // 1 MB int8 packed Wu
  float* sw = (float*)((char*)d_ws + (1 << 20));             // 8 KB col scales

  colscale_kernel<<<8, 256, 0, stream>>>(Wu, sw);
  pack_i8_kernel<<<256, 256, 0, stream>>>(Wu, sw, pk);
  lstm_kernel<<<256, 512, 0, stream>>>(initial, enc_h, enc_c, Wx, bias,
                                       w1, b1, w2, b2, pk, sw, (float*)d_out);
}